// Round 1
// baseline (209.941 us; speedup 1.0000x reference)
//
#include <hip/hip_runtime.h>

// Problem constants
#define B_SZ   8
#define T_SEQ  2048
#define C_DIM  1024
#define H_DIM  128

typedef _Float16 half8   __attribute__((ext_vector_type(8)));
typedef _Float16 half4_t __attribute__((ext_vector_type(4)));
typedef float    f32x4   __attribute__((ext_vector_type(4)));

#define MFMA(a, b, c) __builtin_amdgcn_mfma_f32_16x16x32_f16(a, b, c, 0, 0, 0)

// exp2-fold: scale q by H^-0.5 * log2(e) and use native v_exp_f32 (exp2).
// Saves one v_mul_f32 per exp (16/wave-tile). Falls back to __expf if the
// builtin is unavailable.
#if __has_builtin(__builtin_amdgcn_exp2f)
#define QSCALE 0.12751744416566133f
#define PEXP(x) __builtin_amdgcn_exp2f(x)
#else
#define QSCALE 0.088388347648318447f
#define PEXP(x) __expf(x)
#endif

// ---------------------------------------------------------------------------
// prep: W [C][H] fp32 -> WT [H][C] half (3 weights).  grid (512,3) x 256
// ---------------------------------------------------------------------------
__global__ __launch_bounds__(256) void prep_kernel(
    const float* __restrict__ Wk, const float* __restrict__ Wq,
    const float* __restrict__ Wv, _Float16* __restrict__ WT_all)
{
    const int w = blockIdx.y;
    const float* W = (w == 0) ? Wk : (w == 1) ? Wq : Wv;
    _Float16* dst = WT_all + (size_t)w * (C_DIM * H_DIM);
    int tid = blockIdx.x * 256 + threadIdx.x;
    int c = tid >> 7;
    int h = tid & (H_DIM - 1);
    dst[(size_t)h * C_DIM + c] = (_Float16)W[tid];
}

// ---------------------------------------------------------------------------
// proj: out[m][n] = sum_k x[m][k]*W[k][n], M=16384 K=1024 N=128.
// R7 structure, TRANSPOSED GRID (256,3): n = w*256 + m_idx, so the 3 blocks
// sharing an x stripe are 256 apart in dispatch order -> same (n mod 8) ->
// SAME XCD, and with all 768 blocks co-resident (3/CU) they run concurrently
// -> 2 of 3 x-stripe reads hit the XCD-local L2 instead of HBM/L3.
// w==0 -> k [B*T][H], w==1 -> q, w==2 -> vT [B][H][T] (transposed).
// (unchanged this round — isolating the attn change)
// ---------------------------------------------------------------------------
__global__ __launch_bounds__(256, 3) void proj_kernel(
    const float* __restrict__ x, const _Float16* __restrict__ WT_all,
    _Float16* __restrict__ q, _Float16* __restrict__ k, _Float16* __restrict__ vT)
{
    __shared__ _Float16 xs [64][72];
    __shared__ _Float16 wsh[128][72];

    const int w  = blockIdx.y;
    const int m0 = blockIdx.x * 64;
    const _Float16* WT = WT_all + (size_t)w * (C_DIM * H_DIM);

    const int t    = threadIdx.x;
    const int wave = t >> 6, lane = t & 63;
    const int quad = lane >> 4, l15 = lane & 15;
    const int wm = (wave >> 1) * 32;
    const int wn = (wave & 1) * 64;

    f32x4 acc[2][4] = {};

    for (int k0 = 0; k0 < C_DIM; k0 += 64) {
        __syncthreads();
        {
            const int row_ = t >> 4, col = (t & 15) * 4;
            #pragma unroll
            for (int p = 0; p < 4; ++p) {
                int row = p * 16 + row_;
                float4 f = *(const float4*)(x + (size_t)(m0 + row) * C_DIM + k0 + col);
                half4_t hv = { (_Float16)f.x, (_Float16)f.y, (_Float16)f.z, (_Float16)f.w };
                *(half4_t*)(&xs[row][col]) = hv;
            }
        }
        {
            const int row_ = t >> 3, col = (t & 7) * 8;
            #pragma unroll
            for (int p = 0; p < 4; ++p) {
                int row = p * 32 + row_;
                *(half8*)(&wsh[row][col]) = *(const half8*)(WT + (size_t)row * C_DIM + k0 + col);
            }
        }
        __syncthreads();
        #pragma unroll
        for (int kb = 0; kb < 2; ++kb) {
            half8 af[2], bf[4];
            #pragma unroll
            for (int i = 0; i < 2; ++i)
                af[i] = *(const half8*)(&xs[wm + i * 16 + l15][kb * 32 + quad * 8]);
            #pragma unroll
            for (int j = 0; j < 4; ++j)
                bf[j] = *(const half8*)(&wsh[wn + j * 16 + l15][kb * 32 + quad * 8]);
            #pragma unroll
            for (int i = 0; i < 2; ++i)
                #pragma unroll
                for (int j = 0; j < 4; ++j)
                    acc[i][j] = MFMA(af[i], bf[j], acc[i][j]);
        }
    }

    if (w != 2) {
        _Float16* outN = (w == 0) ? k : q;
        #pragma unroll
        for (int i = 0; i < 2; ++i) {
            int row = m0 + wm + i * 16 + quad * 4;
            #pragma unroll
            for (int j = 0; j < 4; ++j) {
                int col = wn + j * 16 + l15;
                #pragma unroll
                for (int r = 0; r < 4; ++r)
                    outN[(size_t)(row + r) * H_DIM + col] = (_Float16)acc[i][j][r];
            }
        }
    } else {
        #pragma unroll
        for (int i = 0; i < 2; ++i) {
            int grow = m0 + wm + i * 16 + quad * 4;
            int bb = grow >> 11, tp = grow & (T_SEQ - 1);
            #pragma unroll
            for (int j = 0; j < 4; ++j) {
                int h = wn + j * 16 + l15;
                half4_t hv = { (_Float16)acc[i][j][0], (_Float16)acc[i][j][1],
                               (_Float16)acc[i][j][2], (_Float16)acc[i][j][3] };
                *(half4_t*)(vT + ((size_t)bb * H_DIM + h) * T_SEQ + tp) = hv;
            }
        }
    }
}

// ---------------------------------------------------------------------------
// attn: 4 waves/block, qtile 64, kv tile 64, kv-chunk 512.
// R9 CHANGE: K/V LDS staging + both per-tile barriers DELETED. With XCD-batch
// affinity (b = n&7 -> XCD n%8), each XCD's working set is one batch's K+V =
// 1 MB << 4 MB L2, so QK^T / PV B-fragments are read DIRECTLY from global
// (L2-hit, full 64B-line utilization; 4 waves/block share tiles via L1).
// This is the m169 lesson: staging L2-resident data is pure overhead (the
// 2 barriers/tile serialized every wave behind the slowest stager).
// kv-loop is now barrier-free; waves free-run -> s_setprio(1) around the
// MFMA clusters now has role-diversity to arbitrate (m191 regime).
// Also: exp2-fold (QSCALE) removes 16 v_mul_f32 per wave-tile.
// Only the P round-trip (ps, per-wave, no barrier needed) remains in LDS.
// ---------------------------------------------------------------------------
__global__ __launch_bounds__(256, 3) void attn_kernel(
    const _Float16* __restrict__ q, const _Float16* __restrict__ k,
    const _Float16* __restrict__ vT,
    _Float16* __restrict__ pO, float* __restrict__ ml, float* __restrict__ out)
{
    __shared__ _Float16 ps [4][16][72];  // 9216 B (was 45056 with K/V staging)

    const int n = blockIdx.x;
    const int b = n & 7;
    const int u = n >> 3;                // 0..79, heavy-first

    int qt = 31, c = 0;
    {
        int acc = 0;
        #pragma unroll 1
        while (true) {
            int nch = (qt >> 3) + 1;
            if (u < acc + nch) { c = u - acc; break; }
            acc += nch; --qt;
        }
    }
    const bool partial = (qt >= 8);

    const int kt0 = c * 8;
    const int kt1 = min(qt, c * 8 + 7);

    const int t = threadIdx.x;
    const int wave = t >> 6, lane = t & 63;
    const int quad = lane >> 4, l15 = lane & 15;
    const int qrow0 = qt * 64 + wave * 16;

    const _Float16* qb = q  + (size_t)b * T_SEQ * H_DIM;
    const _Float16* kp = k  + (size_t)b * T_SEQ * H_DIM;
    const _Float16* vp = vT + (size_t)b * H_DIM * T_SEQ;

    half8 aq[4];
    #pragma unroll
    for (int i = 0; i < 4; ++i) {
        half8 v = *(const half8*)(qb + (size_t)(qrow0 + l15) * H_DIM + i * 32 + quad * 8);
        #pragma unroll
        for (int j = 0; j < 8; ++j) v[j] = v[j] * (_Float16)QSCALE;
        aq[i] = v;
    }

    f32x4 accO[8] = {};
    float lrun[4] = {0.0f, 0.0f, 0.0f, 0.0f};

    // per-lane base pointers for direct fragment loads
    const _Float16* kfrag = kp + (size_t)l15 * H_DIM + quad * 8;
    const _Float16* vfrag = vp + (size_t)l15 * T_SEQ + quad * 8;

    for (int kt = kt0; kt <= kt1; ++kt) {
        const int kv0 = kt * 64;

        // ---- QK^T: B-fragments direct from global (L2-resident) ----
        f32x4 sacc[4] = {};
        __builtin_amdgcn_s_setprio(1);
        #pragma unroll
        for (int kbi = 0; kbi < 4; ++kbi) {
            #pragma unroll
            for (int nt = 0; nt < 4; ++nt) {
                half8 bf = *(const half8*)(kfrag + (size_t)(kv0 + nt * 16) * H_DIM + kbi * 32);
                sacc[nt] = MFMA(aq[kbi], bf, sacc[nt]);
            }
        }
        __builtin_amdgcn_s_setprio(0);

        if (kv0 + 63 > qrow0) {
            #pragma unroll
            for (int nt = 0; nt < 4; ++nt) {
                int key = kv0 + nt * 16 + l15;
                #pragma unroll
                for (int r = 0; r < 4; ++r) {
                    int qr = qrow0 + quad * 4 + r;
                    if (key > qr) sacc[nt][r] = -1.0e30f;
                }
            }
        }

        #pragma unroll
        for (int nt = 0; nt < 4; ++nt)
            #pragma unroll
            for (int r = 0; r < 4; ++r) {
                float p = PEXP(sacc[nt][r]);
                lrun[r] += p;
                ps[wave][quad * 4 + r][nt * 16 + l15] = (_Float16)p;
            }

        half8 pf0 = *(const half8*)(&ps[wave][l15][quad * 8]);
        half8 pf1 = *(const half8*)(&ps[wave][l15][32 + quad * 8]);

        // ---- PV: V fragments direct from global (vT is [B][H][T]) ----
        __builtin_amdgcn_s_setprio(1);
        #pragma unroll
        for (int nt = 0; nt < 8; ++nt) {
            const _Float16* vr = vfrag + (size_t)(nt * 16) * T_SEQ + kv0;
            half8 vf0 = *(const half8*)(vr);
            half8 vf1 = *(const half8*)(vr + 32);
            accO[nt] = MFMA(pf0, vf0, accO[nt]);
            accO[nt] = MFMA(pf1, vf1, accO[nt]);
        }
        __builtin_amdgcn_s_setprio(0);
    }

    #pragma unroll
    for (int r = 0; r < 4; ++r) {
        lrun[r] += __shfl_xor(lrun[r], 1);
        lrun[r] += __shfl_xor(lrun[r], 2);
        lrun[r] += __shfl_xor(lrun[r], 4);
        lrun[r] += __shfl_xor(lrun[r], 8);
    }

    if (partial) {
        const int pid = b * 72 + u;
        const int urow = wave * 16 + quad * 4;
        #pragma unroll
        for (int nt = 0; nt < 8; ++nt)
            #pragma unroll
            for (int r = 0; r < 4; ++r)
                pO[(size_t)pid * 8192 + (urow + r) * 128 + nt * 16 + l15]
                    = (_Float16)accO[nt][r];
        if (l15 == 0) {
            #pragma unroll
            for (int r = 0; r < 4; ++r)
                ml[(size_t)pid * 64 + urow + r] = lrun[r];
        }
    } else {
        float invl[4];
        #pragma unroll
        for (int r = 0; r < 4; ++r) invl[r] = 1.0f / lrun[r];
        #pragma unroll
        for (int nt = 0; nt < 8; ++nt)
            #pragma unroll
            for (int r = 0; r < 4; ++r)
                out[((size_t)b * T_SEQ + qrow0 + quad * 4 + r) * H_DIM + nt * 16 + l15]
                    = accO[nt][r] * invl[r];
    }
}

// ---------------------------------------------------------------------------
// combine: out = (sum_c pO[c]) / (sum_c l[c]); nc = qt/8+1 in 2..4. (unchanged)
// ---------------------------------------------------------------------------
__global__ __launch_bounds__(256) void attn_combine(
    const _Float16* __restrict__ pO, const float* __restrict__ ml,
    float* __restrict__ out)
{
    const int n  = blockIdx.x;
    const int b  = n & 7;
    const int m  = n >> 3;               // 0..95
    const int rg = m & 3;
    const int qt = 8 + (m >> 2);         // 8..31
    const int nc = (qt >> 3) + 1;        // 2..4

    int u0 = 0;
    #pragma unroll 1
    for (int q2 = 31; q2 > qt; --q2) u0 += (q2 >> 3) + 1;
    const size_t pid0 = (size_t)b * 72 + u0;

    const int t   = threadIdx.x;
    const int row = rg * 16 + (t >> 4);
    const int h   = (t & 15) * 8;

    float lsum = 0.0f;
    #pragma unroll 1
    for (int c = 0; c < nc; ++c)
        lsum += ml[(pid0 + c) * 64 + row];

    float acc[8] = {};
    #pragma unroll 1
    for (int c = 0; c < nc; ++c) {
        half8 po = *(const half8*)(pO + (pid0 + c) * 8192 + row * 128 + h);
        #pragma unroll
        for (int j = 0; j < 8; ++j) acc[j] += (float)po[j];
    }

    const float inv = 1.0f / lsum;
    float* op = out + ((size_t)b * T_SEQ + qt * 64 + row) * H_DIM + h;
    f32x4 o0 = { acc[0] * inv, acc[1] * inv, acc[2] * inv, acc[3] * inv };
    f32x4 o1 = { acc[4] * inv, acc[5] * inv, acc[6] * inv, acc[7] * inv };
    *(f32x4*)(op)     = o0;
    *(f32x4*)(op + 4) = o1;
}

// ---------------------------------------------------------------------------
extern "C" void kernel_launch(void* const* d_in, const int* in_sizes, int n_in,
                              void* d_out, int out_size, void* d_ws, size_t ws_size,
                              hipStream_t stream)
{
    const float* x  = (const float*)d_in[0];
    const float* Wk = (const float*)d_in[1];
    const float* Wq = (const float*)d_in[2];
    const float* Wv = (const float*)d_in[3];
    float* out = (float*)d_out;

    _Float16* ws = (_Float16*)d_ws;
    const size_t NQKV = (size_t)B_SZ * T_SEQ * H_DIM;          // 2,097,152
    _Float16* q_ws  = ws;
    _Float16* k_ws  = ws + NQKV;
    _Float16* vT_ws = ws + 2 * NQKV;
    _Float16* wt_ws = ws + 3 * NQKV;                           // 3*C*H halfs
    _Float16* pO_ws = wt_ws + 3 * (size_t)(C_DIM * H_DIM);     // 576 units * 8192 halfs
    float*    ml_ws = (float*)(pO_ws + (size_t)576 * 8192);    // 576 * 64 floats

    prep_kernel <<<dim3(512, 3), 256, 0, stream>>>(Wk, Wq, Wv, wt_ws);
    proj_kernel <<<dim3(256, 3), 256, 0, stream>>>(x, wt_ws, q_ws, k_ws, vT_ws);
    attn_kernel <<<640, 256, 0, stream>>>(q_ws, k_ws, vT_ws, pO_ws, ml_ws, out);
    attn_combine<<<768, 256, 0, stream>>>(pO_ws, ml_ws, out);
}

// Round 2
// 150.492 us; speedup vs baseline: 1.3950x; 1.3950x over previous
//
#include <hip/hip_runtime.h>

// Problem constants
#define B_SZ   8
#define T_SEQ  2048
#define C_DIM  1024
#define H_DIM  128

typedef _Float16 half8   __attribute__((ext_vector_type(8)));
typedef _Float16 half4_t __attribute__((ext_vector_type(4)));
typedef float    f32x4   __attribute__((ext_vector_type(4)));

#define MFMA(a, b, c) __builtin_amdgcn_mfma_f32_16x16x32_f16(a, b, c, 0, 0, 0)

// exp2-fold: scale q by H^-0.5 * log2(e) and use native v_exp_f32 (exp2).
#if __has_builtin(__builtin_amdgcn_exp2f)
#define QSCALE 0.12751744416566133f
#define PEXP(x) __builtin_amdgcn_exp2f(x)
#else
#define QSCALE 0.088388347648318447f
#define PEXP(x) __expf(x)
#endif

// ---------------------------------------------------------------------------
// prep: W [C][H] fp32 -> WT [H][C] half (3 weights).  grid (512,3) x 256
// ---------------------------------------------------------------------------
__global__ __launch_bounds__(256) void prep_kernel(
    const float* __restrict__ Wk, const float* __restrict__ Wq,
    const float* __restrict__ Wv, _Float16* __restrict__ WT_all)
{
    const int w = blockIdx.y;
    const float* W = (w == 0) ? Wk : (w == 1) ? Wq : Wv;
    _Float16* dst = WT_all + (size_t)w * (C_DIM * H_DIM);
    int tid = blockIdx.x * 256 + threadIdx.x;
    int c = tid >> 7;
    int h = tid & (H_DIM - 1);
    dst[(size_t)h * C_DIM + c] = (_Float16)W[tid];
}

// ---------------------------------------------------------------------------
// proj: out[m][n] = sum_k x[m][k]*W[k][n], M=16384 K=1024 N=128.
// R7 structure + transposed grid (XCD affinity).  R10 CHANGE (T14): next
// K-step's x/W tiles are prefetched into REGISTERS during the MFMA compute,
// so the global-load latency no longer sits exposed between the two
// barriers; the loop-top ds_write consumes already-landed registers.
// ---------------------------------------------------------------------------
__global__ __launch_bounds__(256, 3) void proj_kernel(
    const float* __restrict__ x, const _Float16* __restrict__ WT_all,
    _Float16* __restrict__ q, _Float16* __restrict__ k, _Float16* __restrict__ vT)
{
    __shared__ _Float16 xs [64][72];
    __shared__ _Float16 wsh[128][72];

    const int w  = blockIdx.y;
    const int m0 = blockIdx.x * 64;
    const _Float16* WT = WT_all + (size_t)w * (C_DIM * H_DIM);

    const int t    = threadIdx.x;
    const int wave = t >> 6, lane = t & 63;
    const int quad = lane >> 4, l15 = lane & 15;
    const int wm = (wave >> 1) * 32;
    const int wn = (wave & 1) * 64;

    const int xrow_ = t >> 4, xcol = (t & 15) * 4;
    const int wrow_ = t >> 3, wcol = (t & 7) * 8;

    float4 xf[4];
    half8  wf[4];
    // prologue: load K-step 0 into registers
    #pragma unroll
    for (int p = 0; p < 4; ++p)
        xf[p] = *(const float4*)(x + (size_t)(m0 + p * 16 + xrow_) * C_DIM + xcol);
    #pragma unroll
    for (int p = 0; p < 4; ++p)
        wf[p] = *(const half8*)(WT + (size_t)(p * 32 + wrow_) * C_DIM + wcol);

    f32x4 acc[2][4] = {};

    for (int k0 = 0; k0 < C_DIM; k0 += 64) {
        __syncthreads();
        #pragma unroll
        for (int p = 0; p < 4; ++p) {
            half4_t hv = { (_Float16)xf[p].x, (_Float16)xf[p].y,
                           (_Float16)xf[p].z, (_Float16)xf[p].w };
            *(half4_t*)(&xs[p * 16 + xrow_][xcol]) = hv;
        }
        #pragma unroll
        for (int p = 0; p < 4; ++p)
            *(half8*)(&wsh[p * 32 + wrow_][wcol]) = wf[p];
        __syncthreads();

        // prefetch next K-step while MFMAs run
        if (k0 + 64 < C_DIM) {
            #pragma unroll
            for (int p = 0; p < 4; ++p)
                xf[p] = *(const float4*)(x + (size_t)(m0 + p * 16 + xrow_) * C_DIM + k0 + 64 + xcol);
            #pragma unroll
            for (int p = 0; p < 4; ++p)
                wf[p] = *(const half8*)(WT + (size_t)(p * 32 + wrow_) * C_DIM + k0 + 64 + wcol);
        }

        #pragma unroll
        for (int kb = 0; kb < 2; ++kb) {
            half8 af[2], bf[4];
            #pragma unroll
            for (int i = 0; i < 2; ++i)
                af[i] = *(const half8*)(&xs[wm + i * 16 + l15][kb * 32 + quad * 8]);
            #pragma unroll
            for (int j = 0; j < 4; ++j)
                bf[j] = *(const half8*)(&wsh[wn + j * 16 + l15][kb * 32 + quad * 8]);
            #pragma unroll
            for (int i = 0; i < 2; ++i)
                #pragma unroll
                for (int j = 0; j < 4; ++j)
                    acc[i][j] = MFMA(af[i], bf[j], acc[i][j]);
        }
    }

    if (w != 2) {
        _Float16* outN = (w == 0) ? k : q;
        #pragma unroll
        for (int i = 0; i < 2; ++i) {
            int row = m0 + wm + i * 16 + quad * 4;
            #pragma unroll
            for (int j = 0; j < 4; ++j) {
                int col = wn + j * 16 + l15;
                #pragma unroll
                for (int r = 0; r < 4; ++r)
                    outN[(size_t)(row + r) * H_DIM + col] = (_Float16)acc[i][j][r];
            }
        }
    } else {
        #pragma unroll
        for (int i = 0; i < 2; ++i) {
            int grow = m0 + wm + i * 16 + quad * 4;
            int bb = grow >> 11, tp = grow & (T_SEQ - 1);
            #pragma unroll
            for (int j = 0; j < 4; ++j) {
                int h = wn + j * 16 + l15;
                half4_t hv = { (_Float16)acc[i][j][0], (_Float16)acc[i][j][1],
                               (_Float16)acc[i][j][2], (_Float16)acc[i][j][3] };
                *(half4_t*)(vT + ((size_t)bb * H_DIM + h) * T_SEQ + tp) = hv;
            }
        }
    }
}

// ---------------------------------------------------------------------------
// attn: 4 waves/block, qtile 64, kv tile 64, kv-chunk 512.  R0 staged
// structure RESTORED (R9's direct-global fragment reads were latency-bound:
// MfmaUtil 3.6%, 91 µs).  R10 CHANGE (T14 async-STAGE): next kv-tile's K/V
// loaded into registers during the current tile's QK^T+softmax+PV; the
// loop-top ds_write consumes landed registers, so global latency is hidden
// under compute instead of exposed between the two barriers.
// Kept from R9: exp2-fold QSCALE; s_setprio(1) around MFMA clusters (m191).
// ---------------------------------------------------------------------------
__global__ __launch_bounds__(256, 3) void attn_kernel(
    const _Float16* __restrict__ q, const _Float16* __restrict__ k,
    const _Float16* __restrict__ vT,
    _Float16* __restrict__ pO, float* __restrict__ ml, float* __restrict__ out)
{
    __shared__ _Float16 ks [64][136];    // 17408 B
    __shared__ _Float16 vts[128][72];    // 18432 B
    __shared__ _Float16 ps [4][16][72];  //  9216 B   (total 45056)

    const int n = blockIdx.x;
    const int b = n & 7;
    const int u = n >> 3;                // 0..79, heavy-first

    int qt = 31, c = 0;
    {
        int acc = 0;
        #pragma unroll 1
        while (true) {
            int nch = (qt >> 3) + 1;
            if (u < acc + nch) { c = u - acc; break; }
            acc += nch; --qt;
        }
    }
    const bool partial = (qt >= 8);

    const int kt0 = c * 8;
    const int kt1 = min(qt, c * 8 + 7);

    const int t = threadIdx.x;
    const int wave = t >> 6, lane = t & 63;
    const int quad = lane >> 4, l15 = lane & 15;
    const int qrow0 = qt * 64 + wave * 16;

    const _Float16* qb = q  + (size_t)b * T_SEQ * H_DIM;
    const _Float16* kp = k  + (size_t)b * T_SEQ * H_DIM;
    const _Float16* vp = vT + (size_t)b * H_DIM * T_SEQ;

    half8 aq[4];
    #pragma unroll
    for (int i = 0; i < 4; ++i) {
        half8 v = *(const half8*)(qb + (size_t)(qrow0 + l15) * H_DIM + i * 32 + quad * 8);
        #pragma unroll
        for (int j = 0; j < 8; ++j) v[j] = v[j] * (_Float16)QSCALE;
        aq[i] = v;
    }

    f32x4 accO[8] = {};
    float lrun[4] = {0.0f, 0.0f, 0.0f, 0.0f};

    const int krow = t >> 4, kseg = t & 15;
    const int vrow = t >> 3, vseg = t & 7;

    half8 kreg[4], vreg[4];
    // prologue: load first kv-tile into registers
    {
        const int kv0 = kt0 * 64;
        #pragma unroll
        for (int p = 0; p < 4; ++p)
            kreg[p] = *(const half8*)(kp + (size_t)(kv0 + p * 16 + krow) * H_DIM + kseg * 8);
        #pragma unroll
        for (int p = 0; p < 4; ++p)
            vreg[p] = *(const half8*)(vp + (size_t)(p * 32 + vrow) * T_SEQ + kv0 + vseg * 8);
    }

    for (int kt = kt0; kt <= kt1; ++kt) {
        const int kv0 = kt * 64;
        __syncthreads();
        #pragma unroll
        for (int p = 0; p < 4; ++p)
            *(half8*)(&ks[p * 16 + krow][kseg * 8]) = kreg[p];
        #pragma unroll
        for (int p = 0; p < 4; ++p)
            *(half8*)(&vts[p * 32 + vrow][vseg * 8]) = vreg[p];
        __syncthreads();

        // prefetch next kv-tile into registers while this tile computes
        if (kt < kt1) {
            const int kv1 = kv0 + 64;
            #pragma unroll
            for (int p = 0; p < 4; ++p)
                kreg[p] = *(const half8*)(kp + (size_t)(kv1 + p * 16 + krow) * H_DIM + kseg * 8);
            #pragma unroll
            for (int p = 0; p < 4; ++p)
                vreg[p] = *(const half8*)(vp + (size_t)(p * 32 + vrow) * T_SEQ + kv1 + vseg * 8);
        }

        f32x4 sacc[4] = {};
        __builtin_amdgcn_s_setprio(1);
        #pragma unroll
        for (int kbi = 0; kbi < 4; ++kbi) {
            #pragma unroll
            for (int nt = 0; nt < 4; ++nt) {
                half8 bf = *(const half8*)(&ks[nt * 16 + l15][kbi * 32 + quad * 8]);
                sacc[nt] = MFMA(aq[kbi], bf, sacc[nt]);
            }
        }
        __builtin_amdgcn_s_setprio(0);

        if (kv0 + 63 > qrow0) {
            #pragma unroll
            for (int nt = 0; nt < 4; ++nt) {
                int key = kv0 + nt * 16 + l15;
                #pragma unroll
                for (int r = 0; r < 4; ++r) {
                    int qr = qrow0 + quad * 4 + r;
                    if (key > qr) sacc[nt][r] = -1.0e30f;
                }
            }
        }

        #pragma unroll
        for (int nt = 0; nt < 4; ++nt)
            #pragma unroll
            for (int r = 0; r < 4; ++r) {
                float p = PEXP(sacc[nt][r]);
                lrun[r] += p;
                ps[wave][quad * 4 + r][nt * 16 + l15] = (_Float16)p;
            }

        half8 pf0 = *(const half8*)(&ps[wave][l15][quad * 8]);
        half8 pf1 = *(const half8*)(&ps[wave][l15][32 + quad * 8]);
        __builtin_amdgcn_s_setprio(1);
        #pragma unroll
        for (int nt = 0; nt < 8; ++nt) {
            half8 vf0 = *(const half8*)(&vts[nt * 16 + l15][quad * 8]);
            half8 vf1 = *(const half8*)(&vts[nt * 16 + l15][32 + quad * 8]);
            accO[nt] = MFMA(pf0, vf0, accO[nt]);
            accO[nt] = MFMA(pf1, vf1, accO[nt]);
        }
        __builtin_amdgcn_s_setprio(0);
    }

    #pragma unroll
    for (int r = 0; r < 4; ++r) {
        lrun[r] += __shfl_xor(lrun[r], 1);
        lrun[r] += __shfl_xor(lrun[r], 2);
        lrun[r] += __shfl_xor(lrun[r], 4);
        lrun[r] += __shfl_xor(lrun[r], 8);
    }

    if (partial) {
        const int pid = b * 72 + u;
        const int urow = wave * 16 + quad * 4;
        #pragma unroll
        for (int nt = 0; nt < 8; ++nt)
            #pragma unroll
            for (int r = 0; r < 4; ++r)
                pO[(size_t)pid * 8192 + (urow + r) * 128 + nt * 16 + l15]
                    = (_Float16)accO[nt][r];
        if (l15 == 0) {
            #pragma unroll
            for (int r = 0; r < 4; ++r)
                ml[(size_t)pid * 64 + urow + r] = lrun[r];
        }
    } else {
        float invl[4];
        #pragma unroll
        for (int r = 0; r < 4; ++r) invl[r] = 1.0f / lrun[r];
        #pragma unroll
        for (int nt = 0; nt < 8; ++nt)
            #pragma unroll
            for (int r = 0; r < 4; ++r)
                out[((size_t)b * T_SEQ + qrow0 + quad * 4 + r) * H_DIM + nt * 16 + l15]
                    = accO[nt][r] * invl[r];
    }
}

// ---------------------------------------------------------------------------
// combine: out = (sum_c pO[c]) / (sum_c l[c]); nc = qt/8+1 in 2..4. (unchanged)
// ---------------------------------------------------------------------------
__global__ __launch_bounds__(256) void attn_combine(
    const _Float16* __restrict__ pO, const float* __restrict__ ml,
    float* __restrict__ out)
{
    const int n  = blockIdx.x;
    const int b  = n & 7;
    const int m  = n >> 3;               // 0..95
    const int rg = m & 3;
    const int qt = 8 + (m >> 2);         // 8..31
    const int nc = (qt >> 3) + 1;        // 2..4

    int u0 = 0;
    #pragma unroll 1
    for (int q2 = 31; q2 > qt; --q2) u0 += (q2 >> 3) + 1;
    const size_t pid0 = (size_t)b * 72 + u0;

    const int t   = threadIdx.x;
    const int row = rg * 16 + (t >> 4);
    const int h   = (t & 15) * 8;

    float lsum = 0.0f;
    #pragma unroll 1
    for (int c = 0; c < nc; ++c)
        lsum += ml[(pid0 + c) * 64 + row];

    float acc[8] = {};
    #pragma unroll 1
    for (int c = 0; c < nc; ++c) {
        half8 po = *(const half8*)(pO + (pid0 + c) * 8192 + row * 128 + h);
        #pragma unroll
        for (int j = 0; j < 8; ++j) acc[j] += (float)po[j];
    }

    const float inv = 1.0f / lsum;
    float* op = out + ((size_t)b * T_SEQ + qt * 64 + row) * H_DIM + h;
    f32x4 o0 = { acc[0] * inv, acc[1] * inv, acc[2] * inv, acc[3] * inv };
    f32x4 o1 = { acc[4] * inv, acc[5] * inv, acc[6] * inv, acc[7] * inv };
    *(f32x4*)(op)     = o0;
    *(f32x4*)(op + 4) = o1;
}

// ---------------------------------------------------------------------------
extern "C" void kernel_launch(void* const* d_in, const int* in_sizes, int n_in,
                              void* d_out, int out_size, void* d_ws, size_t ws_size,
                              hipStream_t stream)
{
    const float* x  = (const float*)d_in[0];
    const float* Wk = (const float*)d_in[1];
    const float* Wq = (const float*)d_in[2];
    const float* Wv = (const float*)d_in[3];
    float* out = (float*)d_out;

    _Float16* ws = (_Float16*)d_ws;
    const size_t NQKV = (size_t)B_SZ * T_SEQ * H_DIM;          // 2,097,152
    _Float16* q_ws  = ws;
    _Float16* k_ws  = ws + NQKV;
    _Float16* vT_ws = ws + 2 * NQKV;
    _Float16* wt_ws = ws + 3 * NQKV;                           // 3*C*H halfs
    _Float16* pO_ws = wt_ws + 3 * (size_t)(C_DIM * H_DIM);     // 576 units * 8192 halfs
    float*    ml_ws = (float*)(pO_ws + (size_t)576 * 8192);    // 576 * 64 floats

    prep_kernel <<<dim3(512, 3), 256, 0, stream>>>(Wk, Wq, Wv, wt_ws);
    proj_kernel <<<dim3(256, 3), 256, 0, stream>>>(x, wt_ws, q_ws, k_ws, vT_ws);
    attn_kernel <<<640, 256, 0, stream>>>(q_ws, k_ws, vT_ws, pO_ws, ml_ws, out);
    attn_combine<<<768, 256, 0, stream>>>(pO_ws, ml_ws, out);
}